// Round 1
// baseline (2559.983 us; speedup 1.0000x reference)
//
#include <hip/hip_runtime.h>

#define B_   4
#define N_   4096
#define H_   16
#define DH   64
#define HID  1024
#define NC3  3072
#define M_   256
#define SCALE 0.125f
#define EPS   1e-3f
#define CHUNKS_B 8
#define CHUNKS_C 16

// ---------- Phase 1: qkv = x @ w + bias, routed to q/k/v [BH][N][DH] ----------
__global__ __launch_bounds__(256) void gemm_qkv(
    const float* __restrict__ x, const float* __restrict__ w,
    const float* __restrict__ bias,
    float* __restrict__ q, float* __restrict__ k, float* __restrict__ v)
{
    __shared__ float As[16][68];   // [k][m], padded, 16B-aligned rows (68*4=272=16*17)
    __shared__ float Bs[16][68];   // [k][n]

    const int tid = threadIdx.x;
    const int tx = tid & 15, ty = tid >> 4;
    const int row0 = blockIdx.y * 64;
    const int col0 = blockIdx.x * 64;

    const int lm = tid >> 2;            // 0..63  A-row
    const int lk = (tid & 3) * 4;       // k quad
    const int bk = tid >> 4;            // 0..15  B k-row
    const int bn = (tid & 15) * 4;      // col quad

    float acc[4][4] = {};

    for (int k0 = 0; k0 < HID; k0 += 16) {
        float4 a4 = *(const float4*)(x + (size_t)(row0 + lm) * HID + k0 + lk);
        float4 b4 = *(const float4*)(w + (size_t)(k0 + bk) * NC3 + col0 + bn);
        __syncthreads();   // previous tile's compute must finish before overwrite
        As[lk + 0][lm] = a4.x;
        As[lk + 1][lm] = a4.y;
        As[lk + 2][lm] = a4.z;
        As[lk + 3][lm] = a4.w;
        *(float4*)&Bs[bk][bn] = b4;
        __syncthreads();
#pragma unroll
        for (int kk = 0; kk < 16; ++kk) {
            float4 av = *(const float4*)&As[kk][ty * 4];
            float4 bv = *(const float4*)&Bs[kk][tx * 4];
            float a_[4] = {av.x, av.y, av.z, av.w};
            float b_[4] = {bv.x, bv.y, bv.z, bv.w};
#pragma unroll
            for (int i = 0; i < 4; ++i)
#pragma unroll
                for (int j = 0; j < 4; ++j)
                    acc[i][j] = fmaf(a_[i], b_[j], acc[i][j]);
        }
    }

    // epilogue: whole block tile lies in one (which, h) 64-col band
    const int col = col0 + tx * 4;
    const int which = col >> 10;
    const int h = (col >> 6) & 15;
    const int d = col & 63;
    float* dst = (which == 0) ? q : ((which == 1) ? k : v);
    float4 bb = *(const float4*)(bias + col);
#pragma unroll
    for (int i = 0; i < 4; ++i) {
        const int row = row0 + ty * 4 + i;
        const int bi = row >> 12;       // row / N_
        const int n  = row & (N_ - 1);
        float4 o;
        o.x = acc[i][0] + bb.x; o.y = acc[i][1] + bb.y;
        o.z = acc[i][2] + bb.z; o.w = acc[i][3] + bb.w;
        *(float4*)(dst + ((size_t)((bi * H_ + h) * N_ + n)) * DH + d) = o;
    }
}

// ---------- Phase 2: k' = relu(scale*K.projT)+eps ; ctx += k'^T V ; ksum += sum k' ----------
__global__ __launch_bounds__(256) void kv_context(
    const float* __restrict__ k, const float* __restrict__ v,
    const float* __restrict__ proj,
    float* __restrict__ ctx, float* __restrict__ ksum)
{
    const int m  = threadIdx.x;        // 0..255 feature index
    const int bh = blockIdx.y;         // 0..63
    const int n0 = blockIdx.x * (N_ / CHUNKS_B);

    float pr[64];
#pragma unroll
    for (int d4 = 0; d4 < 16; ++d4) {
        float4 p4 = *(const float4*)(proj + (size_t)m * DH + d4 * 4);
        pr[4 * d4 + 0] = p4.x; pr[4 * d4 + 1] = p4.y;
        pr[4 * d4 + 2] = p4.z; pr[4 * d4 + 3] = p4.w;
    }

    float acc[64] = {};
    float ks = 0.f;
    const float* krow = k + ((size_t)bh * N_ + n0) * DH;
    const float* vrow = v + ((size_t)bh * N_ + n0) * DH;

    for (int n = 0; n < N_ / CHUNKS_B; ++n) {
        const float4* kr4 = (const float4*)(krow + (size_t)n * DH);
        float s0 = 0.f, s1 = 0.f, s2 = 0.f, s3 = 0.f;   // 4 partials: break fma chain
#pragma unroll
        for (int d4 = 0; d4 < 16; ++d4) {
            float4 k4 = kr4[d4];                        // wave-uniform broadcast load
            s0 = fmaf(k4.x, pr[4 * d4 + 0], s0);
            s1 = fmaf(k4.y, pr[4 * d4 + 1], s1);
            s2 = fmaf(k4.z, pr[4 * d4 + 2], s2);
            s3 = fmaf(k4.w, pr[4 * d4 + 3], s3);
        }
        const float kp = fmaxf((s0 + s1 + s2 + s3) * SCALE, 0.f) + EPS;
        ks += kp;
        const float4* vr4 = (const float4*)(vrow + (size_t)n * DH);
#pragma unroll
        for (int d4 = 0; d4 < 16; ++d4) {
            float4 v4 = vr4[d4];                        // wave-uniform broadcast load
            acc[4 * d4 + 0] = fmaf(kp, v4.x, acc[4 * d4 + 0]);
            acc[4 * d4 + 1] = fmaf(kp, v4.y, acc[4 * d4 + 1]);
            acc[4 * d4 + 2] = fmaf(kp, v4.z, acc[4 * d4 + 2]);
            acc[4 * d4 + 3] = fmaf(kp, v4.w, acc[4 * d4 + 3]);
        }
    }

    float* cdst = ctx + ((size_t)bh * M_ + m) * DH;
#pragma unroll
    for (int d = 0; d < 64; ++d) atomicAdd(cdst + d, acc[d]);
    atomicAdd(ksum + bh * M_ + m, ks);
}

// ---------- Phase 3: q' = relu(scale*Q.projT)+eps ; out = (q' ctx) / (q'.ksum) ----------
__global__ __launch_bounds__(256) void attn_out(
    const float* __restrict__ q, const float* __restrict__ proj,
    const float* __restrict__ ctx, const float* __restrict__ ksum,
    float* __restrict__ out)
{
    __shared__ float ctx_s[M_ * DH];   // 64 KB, broadcast-read (no conflicts)
    __shared__ float ks_s[M_];

    const int tid = threadIdx.x;
    const int bh = blockIdx.y;
    const int bi = bh >> 4, h = bh & 15;
    const int n  = blockIdx.x * 256 + tid;

    for (int i = tid; i < M_ * DH / 4; i += 256)
        *(float4*)&ctx_s[i * 4] = *(const float4*)(ctx + (size_t)bh * M_ * DH + i * 4);
    ks_s[tid] = ksum[bh * M_ + tid];
    __syncthreads();

    float qr[64];
#pragma unroll
    for (int d4 = 0; d4 < 16; ++d4) {
        float4 q4 = *(const float4*)(q + ((size_t)bh * N_ + n) * DH + d4 * 4);
        qr[4 * d4 + 0] = q4.x; qr[4 * d4 + 1] = q4.y;
        qr[4 * d4 + 2] = q4.z; qr[4 * d4 + 3] = q4.w;
    }

    float o[64] = {};
    float den = 0.f;
    for (int mi = 0; mi < M_; ++mi) {
        const float4* prow = (const float4*)(proj + (size_t)mi * DH);
        float s0 = 0.f, s1 = 0.f, s2 = 0.f, s3 = 0.f;
#pragma unroll
        for (int d4 = 0; d4 < 16; ++d4) {
            float4 p4 = prow[d4];                      // wave-uniform broadcast (L2-hot)
            s0 = fmaf(qr[4 * d4 + 0], p4.x, s0);
            s1 = fmaf(qr[4 * d4 + 1], p4.y, s1);
            s2 = fmaf(qr[4 * d4 + 2], p4.z, s2);
            s3 = fmaf(qr[4 * d4 + 3], p4.w, s3);
        }
        const float qp = fmaxf((s0 + s1 + s2 + s3) * SCALE, 0.f) + EPS;
        den = fmaf(qp, ks_s[mi], den);
#pragma unroll
        for (int d4 = 0; d4 < 16; ++d4) {
            float4 c4 = *(const float4*)&ctx_s[mi * DH + d4 * 4];   // LDS broadcast
            o[4 * d4 + 0] = fmaf(qp, c4.x, o[4 * d4 + 0]);
            o[4 * d4 + 1] = fmaf(qp, c4.y, o[4 * d4 + 1]);
            o[4 * d4 + 2] = fmaf(qp, c4.z, o[4 * d4 + 2]);
            o[4 * d4 + 3] = fmaf(qp, c4.w, o[4 * d4 + 3]);
        }
    }

    const float dinv = 1.f / den;
    float* dst = out + ((size_t)(bi * N_ + n)) * HID + h * DH;
#pragma unroll
    for (int d4 = 0; d4 < 16; ++d4) {
        float4 o4;
        o4.x = o[4 * d4 + 0] * dinv; o4.y = o[4 * d4 + 1] * dinv;
        o4.z = o[4 * d4 + 2] * dinv; o4.w = o[4 * d4 + 3] * dinv;
        *(float4*)(dst + d4 * 4) = o4;
    }
}

extern "C" void kernel_launch(void* const* d_in, const int* in_sizes, int n_in,
                              void* d_out, int out_size, void* d_ws, size_t ws_size,
                              hipStream_t stream) {
    const float* x    = (const float*)d_in[0];
    const float* w    = (const float*)d_in[1];
    const float* bias = (const float*)d_in[2];
    const float* proj = (const float*)d_in[3];
    float* out = (float*)d_out;
    float* ws  = (float*)d_ws;

    const size_t qkv_elems = (size_t)B_ * H_ * N_ * DH;   // 16,777,216 each
    const size_t ctx_elems = (size_t)B_ * H_ * M_ * DH;   // 4,194,304
    const size_t ksum_elems = (size_t)B_ * H_ * M_;       // 16,384

    float* q    = ws;
    float* k    = ws + qkv_elems;
    float* v    = ws + 2 * qkv_elems;
    float* ctx  = ws + 3 * qkv_elems;
    float* ksum = ctx + ctx_elems;

    // ctx/ksum are accumulated with atomics — zero them (ws is poisoned 0xAA)
    hipMemsetAsync(ctx, 0, (ctx_elems + ksum_elems) * sizeof(float), stream);

    dim3 gA(NC3 / 64, (B_ * N_) / 64);   // (48, 256)
    gemm_qkv<<<gA, 256, 0, stream>>>(x, w, bias, q, k, v);

    dim3 gB(CHUNKS_B, B_ * H_);          // (8, 64)
    kv_context<<<gB, 256, 0, stream>>>(k, v, proj, ctx, ksum);

    dim3 gC(CHUNKS_C, B_ * H_);          // (16, 64)
    attn_out<<<gC, 256, 0, stream>>>(q, proj, ctx, ksum, out);
}

// Round 2
// 1386.174 us; speedup vs baseline: 1.8468x; 1.8468x over previous
//
#include <hip/hip_runtime.h>

#define B_   4
#define N_   4096
#define H_   16
#define DH   64
#define HID  1024
#define NC3  3072
#define M_   256
#define SCALE 0.125f
#define EPS   1e-3f
#define CHUNKS_B 8
#define CHUNKS_C 16

typedef _Float16 half8 __attribute__((ext_vector_type(8)));
typedef float floatx4 __attribute__((ext_vector_type(4)));

// async global->LDS, 16B per lane; LDS dest = uniform base + lane*16 (HW rule)
#define GLD_LDS16(gptr, lds_base) \
  __builtin_amdgcn_global_load_lds((const __attribute__((address_space(1))) void*)(gptr), \
                                   (__attribute__((address_space(3))) void*)(lds_base), 16, 0, 0)

// ---------- Phase 0: wT[n][k] = (f16) w[k][n] ----------
__global__ __launch_bounds__(256) void convert_wT(
    const float* __restrict__ w, _Float16* __restrict__ wT)
{
    __shared__ float t[64][65];
    const int tid = threadIdx.x;
    const int kb = blockIdx.y * 64;
    const int nb = blockIdx.x * 64;
    const int c = tid & 63, r0 = tid >> 6;
#pragma unroll
    for (int rr = 0; rr < 64; rr += 4)
        t[rr + r0][c] = w[(size_t)(kb + rr + r0) * NC3 + nb + c];
    __syncthreads();
#pragma unroll
    for (int rr = 0; rr < 64; rr += 4)
        wT[(size_t)(nb + rr + r0) * HID + kb + c] = (_Float16)t[c][rr + r0];
}

// ---------- Phase 1: qkv = x @ w + bias via f16 MFMA, routed to q/k/v [BH][N][64] ----------
// A tile: 128 rows x 32 k, fp32 in LDS (converted to f16 at frag load).
//   LDS blocks of 16B (4 fp32); block pos = dataquad ^ (row & 7)  -> <=2-way banks
// B tile: 128 cols x 32 k, f16 in LDS (from pre-transposed wT).
//   LDS blocks of 16B (8 f16);  block pos = dataoct ^ ((row>>1) & 3)
__global__ __launch_bounds__(256) void gemm_qkv_mfma(
    const float* __restrict__ x, const _Float16* __restrict__ wT,
    const float* __restrict__ bias,
    float* __restrict__ q, float* __restrict__ k, float* __restrict__ v)
{
    __shared__ __align__(16) float    As[128 * 32];   // 16 KB
    __shared__ __align__(16) _Float16 Bs[128 * 32];   // 8 KB

    const int tid  = threadIdx.x;
    const int lane = tid & 63;
    const int wv   = tid >> 6;
    const int row0 = blockIdx.y * 128;
    const int col0 = blockIdx.x * 128;

    const int wm = (wv & 1) * 64;     // wave's 64x64 sub-tile
    const int wn = (wv >> 1) * 64;
    const int lr = lane & 15;
    const int lg = lane >> 4;

    const int a_r = lane >> 3;        // A staging: 8 rows / inst
    const int a_q = lane & 7;
    const int b_r = lane >> 2;        // B staging: 16 rows / inst
    const int b_q = lane & 3;

    floatx4 acc[4][4] = {};

    for (int k0 = 0; k0 < HID; k0 += 32) {
        // ---- stage A: 4 insts/wave, fp32, swizzled ----
#pragma unroll
        for (int s = 0; s < 4; ++s) {
            const int R  = wv * 32 + s * 8;
            const int r  = R + a_r;
            const int qd = a_q ^ (r & 7);
            const float* g = x + (size_t)(row0 + r) * HID + k0 + 4 * qd;
            GLD_LDS16(g, (char*)As + R * 128);
        }
        // ---- stage B: 2 insts/wave, f16, swizzled ----
#pragma unroll
        for (int s = 0; s < 2; ++s) {
            const int R  = wv * 32 + s * 16;
            const int r  = R + b_r;
            const int qd = b_q ^ ((r >> 1) & 3);
            const _Float16* g = wT + (size_t)(col0 + r) * HID + k0 + 8 * qd;
            GLD_LDS16(g, (char*)Bs + R * 64);
        }
        __syncthreads();   // drains vmcnt(0): staged data visible

        half8 af[4], bf[4];
#pragma unroll
        for (int i = 0; i < 4; ++i) {
            const int m  = wm + 16 * i + lr;
            const int p0 = (2 * lg) ^ (m & 7);
            const int p1 = (2 * lg + 1) ^ (m & 7);
            floatx4 lo = *(const floatx4*)((const char*)As + m * 128 + p0 * 16);
            floatx4 hi = *(const floatx4*)((const char*)As + m * 128 + p1 * 16);
            half8 a;
            a[0] = (_Float16)lo[0]; a[1] = (_Float16)lo[1];
            a[2] = (_Float16)lo[2]; a[3] = (_Float16)lo[3];
            a[4] = (_Float16)hi[0]; a[5] = (_Float16)hi[1];
            a[6] = (_Float16)hi[2]; a[7] = (_Float16)hi[3];
            af[i] = a;
        }
#pragma unroll
        for (int j = 0; j < 4; ++j) {
            const int n = wn + 16 * j + lr;
            const int p = lg ^ ((n >> 1) & 3);
            bf[j] = *(const half8*)((const char*)Bs + n * 64 + p * 16);
        }
#pragma unroll
        for (int i = 0; i < 4; ++i)
#pragma unroll
            for (int j = 0; j < 4; ++j)
                acc[i][j] = __builtin_amdgcn_mfma_f32_16x16x32_f16(af[i], bf[j], acc[i][j], 0, 0, 0);
        __syncthreads();   // all waves done reading before next stage overwrites
    }

    // epilogue: D[m][n], m = wm+16i+4*lg+reg, n = wn+16j+lr  (m89-verified layout)
#pragma unroll
    for (int j = 0; j < 4; ++j) {
        const int col = col0 + wn + 16 * j + lr;
        const int which = col >> 10, h = (col >> 6) & 15, d = col & 63;
        float* dst = (which == 0) ? q : ((which == 1) ? k : v);
        const float bb = bias[col];
#pragma unroll
        for (int i = 0; i < 4; ++i)
#pragma unroll
            for (int rg = 0; rg < 4; ++rg) {
                const int m  = row0 + wm + 16 * i + 4 * lg + rg;
                const int bi = m >> 12, n = m & (N_ - 1);
                dst[((size_t)((bi * H_ + h) * N_ + n)) * DH + d] = acc[i][j][rg] + bb;
            }
    }
}

// ---------- Phase 2: k' = relu(scale*K.projT)+eps ; ctx += k'^T V ; ksum += sum k' ----------
__global__ __launch_bounds__(256) void kv_context(
    const float* __restrict__ k, const float* __restrict__ v,
    const float* __restrict__ proj,
    float* __restrict__ ctx, float* __restrict__ ksum)
{
    const int m  = threadIdx.x;
    const int bh = blockIdx.y;
    const int n0 = blockIdx.x * (N_ / CHUNKS_B);

    float pr[64];
#pragma unroll
    for (int d4 = 0; d4 < 16; ++d4) {
        float4 p4 = *(const float4*)(proj + (size_t)m * DH + d4 * 4);
        pr[4 * d4 + 0] = p4.x; pr[4 * d4 + 1] = p4.y;
        pr[4 * d4 + 2] = p4.z; pr[4 * d4 + 3] = p4.w;
    }

    float acc[64] = {};
    float ks = 0.f;
    const float* krow = k + ((size_t)bh * N_ + n0) * DH;
    const float* vrow = v + ((size_t)bh * N_ + n0) * DH;

    for (int n = 0; n < N_ / CHUNKS_B; ++n) {
        const float4* kr4 = (const float4*)(krow + (size_t)n * DH);
        float s0 = 0.f, s1 = 0.f, s2 = 0.f, s3 = 0.f;
#pragma unroll
        for (int d4 = 0; d4 < 16; ++d4) {
            float4 k4 = kr4[d4];
            s0 = fmaf(k4.x, pr[4 * d4 + 0], s0);
            s1 = fmaf(k4.y, pr[4 * d4 + 1], s1);
            s2 = fmaf(k4.z, pr[4 * d4 + 2], s2);
            s3 = fmaf(k4.w, pr[4 * d4 + 3], s3);
        }
        const float kp = fmaxf((s0 + s1 + s2 + s3) * SCALE, 0.f) + EPS;
        ks += kp;
        const float4* vr4 = (const float4*)(vrow + (size_t)n * DH);
#pragma unroll
        for (int d4 = 0; d4 < 16; ++d4) {
            float4 v4 = vr4[d4];
            acc[4 * d4 + 0] = fmaf(kp, v4.x, acc[4 * d4 + 0]);
            acc[4 * d4 + 1] = fmaf(kp, v4.y, acc[4 * d4 + 1]);
            acc[4 * d4 + 2] = fmaf(kp, v4.z, acc[4 * d4 + 2]);
            acc[4 * d4 + 3] = fmaf(kp, v4.w, acc[4 * d4 + 3]);
        }
    }

    float* cdst = ctx + ((size_t)bh * M_ + m) * DH;
#pragma unroll
    for (int d = 0; d < 64; ++d) atomicAdd(cdst + d, acc[d]);
    atomicAdd(ksum + bh * M_ + m, ks);
}

// ---------- Phase 3: q' = relu(scale*Q.projT)+eps ; out = (q' ctx) / (q'.ksum) ----------
__global__ __launch_bounds__(256) void attn_out(
    const float* __restrict__ q, const float* __restrict__ proj,
    const float* __restrict__ ctx, const float* __restrict__ ksum,
    float* __restrict__ out)
{
    __shared__ float ctx_s[M_ * DH];
    __shared__ float ks_s[M_];

    const int tid = threadIdx.x;
    const int bh = blockIdx.y;
    const int bi = bh >> 4, h = bh & 15;
    const int n  = blockIdx.x * 256 + tid;

    for (int i = tid; i < M_ * DH / 4; i += 256)
        *(float4*)&ctx_s[i * 4] = *(const float4*)(ctx + (size_t)bh * M_ * DH + i * 4);
    ks_s[tid] = ksum[bh * M_ + tid];
    __syncthreads();

    float qr[64];
#pragma unroll
    for (int d4 = 0; d4 < 16; ++d4) {
        float4 q4 = *(const float4*)(q + ((size_t)bh * N_ + n) * DH + d4 * 4);
        qr[4 * d4 + 0] = q4.x; qr[4 * d4 + 1] = q4.y;
        qr[4 * d4 + 2] = q4.z; qr[4 * d4 + 3] = q4.w;
    }

    float o[64] = {};
    float den = 0.f;
    for (int mi = 0; mi < M_; ++mi) {
        const float4* prow = (const float4*)(proj + (size_t)mi * DH);
        float s0 = 0.f, s1 = 0.f, s2 = 0.f, s3 = 0.f;
#pragma unroll
        for (int d4 = 0; d4 < 16; ++d4) {
            float4 p4 = prow[d4];
            s0 = fmaf(qr[4 * d4 + 0], p4.x, s0);
            s1 = fmaf(qr[4 * d4 + 1], p4.y, s1);
            s2 = fmaf(qr[4 * d4 + 2], p4.z, s2);
            s3 = fmaf(qr[4 * d4 + 3], p4.w, s3);
        }
        const float qp = fmaxf((s0 + s1 + s2 + s3) * SCALE, 0.f) + EPS;
        den = fmaf(qp, ks_s[mi], den);
#pragma unroll
        for (int d4 = 0; d4 < 16; ++d4) {
            float4 c4 = *(const float4*)&ctx_s[mi * DH + d4 * 4];
            o[4 * d4 + 0] = fmaf(qp, c4.x, o[4 * d4 + 0]);
            o[4 * d4 + 1] = fmaf(qp, c4.y, o[4 * d4 + 1]);
            o[4 * d4 + 2] = fmaf(qp, c4.z, o[4 * d4 + 2]);
            o[4 * d4 + 3] = fmaf(qp, c4.w, o[4 * d4 + 3]);
        }
    }

    const float dinv = 1.f / den;
    float* dst = out + ((size_t)(bi * N_ + n)) * HID + h * DH;
#pragma unroll
    for (int d4 = 0; d4 < 16; ++d4) {
        float4 o4;
        o4.x = o[4 * d4 + 0] * dinv; o4.y = o[4 * d4 + 1] * dinv;
        o4.z = o[4 * d4 + 2] * dinv; o4.w = o[4 * d4 + 3] * dinv;
        *(float4*)(dst + d4 * 4) = o4;
    }
}

extern "C" void kernel_launch(void* const* d_in, const int* in_sizes, int n_in,
                              void* d_out, int out_size, void* d_ws, size_t ws_size,
                              hipStream_t stream) {
    const float* x    = (const float*)d_in[0];
    const float* w    = (const float*)d_in[1];
    const float* bias = (const float*)d_in[2];
    const float* proj = (const float*)d_in[3];
    float* out = (float*)d_out;
    float* ws  = (float*)d_ws;

    const size_t qkv_elems  = (size_t)B_ * H_ * N_ * DH;   // 16,777,216 each
    const size_t ctx_elems  = (size_t)B_ * H_ * M_ * DH;   // 4,194,304
    const size_t ksum_elems = (size_t)B_ * H_ * M_;        // 16,384

    float* q    = ws;
    float* k    = ws + qkv_elems;
    float* v    = ws + 2 * qkv_elems;
    float* ctx  = ws + 3 * qkv_elems;
    float* ksum = ctx + ctx_elems;
    // wT (6.3 MB) aliases ctx (16.8 MB): live only until gemm completes,
    // ctx is memset AFTER the gemm (stream-ordered).
    _Float16* wT = (_Float16*)ctx;

    dim3 gW(NC3 / 64, HID / 64);          // (48, 16)
    convert_wT<<<gW, 256, 0, stream>>>(w, wT);

    dim3 gA(NC3 / 128, (B_ * N_) / 128);  // (24, 128)
    gemm_qkv_mfma<<<gA, 256, 0, stream>>>(x, wT, bias, q, k, v);

    hipMemsetAsync(ctx, 0, (ctx_elems + ksum_elems) * sizeof(float), stream);

    dim3 gB(CHUNKS_B, B_ * H_);           // (8, 64)
    kv_context<<<gB, 256, 0, stream>>>(k, v, proj, ctx, ksum);

    dim3 gC(CHUNKS_C, B_ * H_);           // (16, 64)
    attn_out<<<gC, 256, 0, stream>>>(q, proj, ctx, ksum, out);
}

// Round 3
// 410.475 us; speedup vs baseline: 6.2366x; 3.3770x over previous
//
#include <hip/hip_runtime.h>

#define B_   4
#define N_   4096
#define NH   16
#define DH   64
#define HID  1024
#define NC3  3072
#define M_   256
#define BH   64
#define SCALE 0.125f
#define EPS   1e-3f
#define CH2  8
#define CH3  16

typedef _Float16 half8  __attribute__((ext_vector_type(8)));
typedef _Float16 half4v __attribute__((ext_vector_type(4)));
typedef float floatx4   __attribute__((ext_vector_type(4)));

#define GLD_LDS16(gptr, lds_base) \
  __builtin_amdgcn_global_load_lds((const __attribute__((address_space(1))) void*)(gptr), \
                                   (__attribute__((address_space(3))) void*)(lds_base), 16, 0, 0)

// ---------- wT[n][k] = (f16) w[k][n] ----------
__global__ __launch_bounds__(256) void convert_wT(
    const float* __restrict__ w, _Float16* __restrict__ wT)
{
    __shared__ float t[64][65];
    const int tid = threadIdx.x;
    const int kb = blockIdx.y * 64, nb = blockIdx.x * 64;
    const int c = tid & 63, r0 = tid >> 6;
#pragma unroll
    for (int rr = 0; rr < 64; rr += 4)
        t[rr + r0][c] = w[(size_t)(kb + rr + r0) * NC3 + nb + c];
    __syncthreads();
#pragma unroll
    for (int rr = 0; rr < 64; rr += 4)
        wT[(size_t)(nb + rr + r0) * HID + kb + c] = (_Float16)t[c][rr + r0];
}

// ---------- projh = (f16) proj ----------
__global__ __launch_bounds__(256) void convert_projh(
    const float* __restrict__ proj, _Float16* __restrict__ projh)
{
    const int i = blockIdx.x * 256 + threadIdx.x;
    projh[i] = (_Float16)proj[i];
}

// ---------- Phase 1: qkv GEMM (f16 MFMA) -> qh,kh [bh][n][d] (scaled), vTh [bh][d][n] ----------
__global__ __launch_bounds__(256) void gemm_qkv_mfma(
    const float* __restrict__ x, const _Float16* __restrict__ wT,
    const float* __restrict__ bias,
    _Float16* __restrict__ qh, _Float16* __restrict__ kh, _Float16* __restrict__ vTh)
{
    __shared__ __align__(16) float    As[128 * 32];
    __shared__ __align__(16) _Float16 Bs[128 * 32];

    const int tid  = threadIdx.x;
    const int lane = tid & 63;
    const int wv   = tid >> 6;
    const int row0 = blockIdx.y * 128;
    const int col0 = blockIdx.x * 128;

    const int wm = (wv & 1) * 64;
    const int wn = (wv >> 1) * 64;
    const int lr = lane & 15;
    const int lg = lane >> 4;

    const int a_r = lane >> 3, a_q = lane & 7;
    const int b_r = lane >> 2, b_q = lane & 3;

    floatx4 acc[4][4] = {};

    for (int k0 = 0; k0 < HID; k0 += 32) {
#pragma unroll
        for (int s = 0; s < 4; ++s) {
            const int R = wv * 32 + s * 8;
            const int r = R + a_r;
            const int qd = a_q ^ (r & 7);
            GLD_LDS16(x + (size_t)(row0 + r) * HID + k0 + 4 * qd, (char*)As + R * 128);
        }
#pragma unroll
        for (int s = 0; s < 2; ++s) {
            const int R = wv * 32 + s * 16;
            const int r = R + b_r;
            const int qd = b_q ^ ((r >> 1) & 3);
            GLD_LDS16(wT + (size_t)(col0 + r) * HID + k0 + 8 * qd, (char*)Bs + R * 64);
        }
        __syncthreads();

        half8 af[4], bf[4];
#pragma unroll
        for (int i = 0; i < 4; ++i) {
            const int m  = wm + 16 * i + lr;
            const int p0 = (2 * lg) ^ (m & 7);
            const int p1 = (2 * lg + 1) ^ (m & 7);
            floatx4 lo = *(const floatx4*)((const char*)As + m * 128 + p0 * 16);
            floatx4 hi = *(const floatx4*)((const char*)As + m * 128 + p1 * 16);
            half8 a;
            a[0] = (_Float16)lo[0]; a[1] = (_Float16)lo[1];
            a[2] = (_Float16)lo[2]; a[3] = (_Float16)lo[3];
            a[4] = (_Float16)hi[0]; a[5] = (_Float16)hi[1];
            a[6] = (_Float16)hi[2]; a[7] = (_Float16)hi[3];
            af[i] = a;
        }
#pragma unroll
        for (int j = 0; j < 4; ++j) {
            const int n = wn + 16 * j + lr;
            const int p = lg ^ ((n >> 1) & 3);
            bf[j] = *(const half8*)((const char*)Bs + n * 64 + p * 16);
        }
#pragma unroll
        for (int i = 0; i < 4; ++i)
#pragma unroll
            for (int j = 0; j < 4; ++j)
                acc[i][j] = __builtin_amdgcn_mfma_f32_16x16x32_f16(af[i], bf[j], acc[i][j], 0, 0, 0);
        __syncthreads();
    }

    // which is block-uniform (col0 multiple of 128, bands of 1024)
#pragma unroll
    for (int j = 0; j < 4; ++j) {
        const int col = col0 + wn + 16 * j + lr;
        const int which = col >> 10;
        const int h = (col >> 6) & 15;
        const int d = col & 63;
        const float bb = bias[col];
        if (which == 2) {
#pragma unroll
            for (int i = 0; i < 4; ++i) {
                const int m0 = row0 + wm + 16 * i + 4 * lg;
                const int bi = m0 >> 12, n0 = m0 & (N_ - 1);
                half4v hv;
#pragma unroll
                for (int rg = 0; rg < 4; ++rg) hv[rg] = (_Float16)(acc[i][j][rg] + bb);
                *(half4v*)(vTh + ((size_t)(bi * NH + h) * DH + d) * N_ + n0) = hv;
            }
        } else {
            _Float16* dst = (which == 0) ? qh : kh;
#pragma unroll
            for (int i = 0; i < 4; ++i)
#pragma unroll
                for (int rg = 0; rg < 4; ++rg) {
                    const int m = row0 + wm + 16 * i + 4 * lg + rg;
                    const int bi = m >> 12, n = m & (N_ - 1);
                    dst[((size_t)(bi * NH + h) * N_ + n) * DH + d] =
                        (_Float16)((acc[i][j][rg] + bb) * SCALE);
                }
        }
    }
}

// ---------- Phase 2: per (chunk,bh): ctxT_part[d][m] = sum_n vT[d][n] * k'[n][m] ----------
__global__ __launch_bounds__(256) void kv_ctx_mfma(
    const _Float16* __restrict__ kh, const _Float16* __restrict__ vTh,
    const _Float16* __restrict__ projh,
    float* __restrict__ ctx_part, float* __restrict__ ksum_part)
{
    __shared__ __align__(16) _Float16 Kt[64 * 64];   // [n][d] swizzled
    __shared__ __align__(16) _Float16 Vt[64 * 64];   // [d][n] swizzled
    __shared__ __align__(16) _Float16 Sp[256 * 64];  // [m][n] swizzled, wave-private slices

    const int tid  = threadIdx.x;
    const int lane = tid & 63;
    const int wv   = tid >> 6;
    const int lr = lane & 15, lg = lane >> 4;
    const int bh = blockIdx.y, chunk = blockIdx.x;
    const int n_base = chunk * (N_ / CH2);

    // proj B-frags: col m = 64wv+16j+lr, k=d
    half8 bfP[4][2];
#pragma unroll
    for (int j = 0; j < 4; ++j)
#pragma unroll
        for (int ks = 0; ks < 2; ++ks)
            bfP[j][ks] = *(const half8*)(projh + (size_t)(64 * wv + 16 * j + lr) * DH + 32 * ks + 8 * lg);

    floatx4 cacc[4][4] = {};            // ctxT acc: i->d-tiles, j->m-tiles
    float ks_acc[4] = {0.f, 0.f, 0.f, 0.f};

    for (int t = 0; t < (N_ / CH2) / 64; ++t) {
        const int n0 = n_base + t * 64;
        __syncthreads();                 // prev-iter Kt/Vt reads done
#pragma unroll
        for (int s = 0; s < 2; ++s) {
            const int R = wv * 16 + s * 8;
            const int r = R + (lane >> 3);
            const int db = (lane & 7) ^ (r & 7);
            GLD_LDS16(kh + ((size_t)(bh * N_ + n0 + r)) * DH + db * 8, (char*)Kt + R * 128);
        }
#pragma unroll
        for (int s = 0; s < 2; ++s) {
            const int R = wv * 16 + s * 8;
            const int r = R + (lane >> 3);
            const int db = (lane & 7) ^ (r & 7);
            GLD_LDS16(vTh + ((size_t)(bh * DH + r)) * N_ + n0 + db * 8, (char*)Vt + R * 128);
        }
        __syncthreads();

        // #1: S[n][m] = Kt . projh^T
        floatx4 s[4][4] = {};
#pragma unroll
        for (int ks = 0; ks < 2; ++ks) {
            half8 aK[4];
#pragma unroll
            for (int i = 0; i < 4; ++i) {
                const int r = 16 * i + lr;
                aK[i] = *(const half8*)((const char*)Kt + r * 128 + (((4 * ks + lg) ^ (r & 7)) * 16));
            }
#pragma unroll
            for (int i = 0; i < 4; ++i)
#pragma unroll
                for (int j = 0; j < 4; ++j)
                    s[i][j] = __builtin_amdgcn_mfma_f32_16x16x32_f16(aK[i], bfP[j][ks], s[i][j], 0, 0, 0);
        }
        // relu+eps -> f16 -> Sp[m][n] (wave-private), ksum accumulate
#pragma unroll
        for (int i = 0; i < 4; ++i)
#pragma unroll
            for (int j = 0; j < 4; ++j) {
                const int m = 64 * wv + 16 * j + lr;
                const int nn0 = 16 * i + 4 * lg;
                half4v h4;
#pragma unroll
                for (int rg = 0; rg < 4; ++rg) {
                    const float kv = fmaxf(s[i][j][rg], 0.f) + EPS;
                    ks_acc[j] += kv;
                    h4[rg] = (_Float16)kv;
                }
                const int db = nn0 >> 3, sub = nn0 & 7;
                *(half4v*)((char*)Sp + m * 128 + ((db ^ (m & 7)) * 16) + sub * 2) = h4;
            }
        // #2: ctxT[d][m-slice] += Vt . Sp   (wave-private Sp: no barrier)
#pragma unroll
        for (int ks = 0; ks < 2; ++ks) {
            half8 aV[4], bS[4];
#pragma unroll
            for (int i = 0; i < 4; ++i) {
                const int r = 16 * i + lr;
                aV[i] = *(const half8*)((const char*)Vt + r * 128 + (((4 * ks + lg) ^ (r & 7)) * 16));
            }
#pragma unroll
            for (int j = 0; j < 4; ++j) {
                const int m = 64 * wv + 16 * j + lr;
                bS[j] = *(const half8*)((const char*)Sp + m * 128 + (((4 * ks + lg) ^ (m & 7)) * 16));
            }
#pragma unroll
            for (int i = 0; i < 4; ++i)
#pragma unroll
                for (int j = 0; j < 4; ++j)
                    cacc[i][j] = __builtin_amdgcn_mfma_f32_16x16x32_f16(aV[i], bS[j], cacc[i][j], 0, 0, 0);
        }
    }

    // ctx_part[chunk][bh][d][m]
#pragma unroll
    for (int i = 0; i < 4; ++i)
#pragma unroll
        for (int j = 0; j < 4; ++j)
#pragma unroll
            for (int rg = 0; rg < 4; ++rg) {
                const int d = 16 * i + 4 * lg + rg;
                const int m = 64 * wv + 16 * j + lr;
                ctx_part[(((size_t)chunk * BH + bh) * DH + d) * M_ + m] = cacc[i][j][rg];
            }
#pragma unroll
    for (int j = 0; j < 4; ++j) {
        float v = ks_acc[j];
        v += __shfl_xor(v, 16);
        v += __shfl_xor(v, 32);
        if (lg == 0)
            ksum_part[((size_t)chunk * BH + bh) * M_ + 64 * wv + 16 * j + lr] = v;
    }
}

// ---------- reduce partials -> ctxTh f16 [bh][d][m], ksumh f16 [bh][m] ----------
__global__ __launch_bounds__(256) void reduce_ctx(
    const float* __restrict__ ctx_part, const float* __restrict__ ksum_part,
    _Float16* __restrict__ ctxTh, _Float16* __restrict__ ksumh)
{
    const int idx = blockIdx.x * 256 + threadIdx.x;
    const int CTX = BH * DH * M_;        // 1,048,576
    if (idx < CTX) {
        float sum = 0.f;
#pragma unroll
        for (int c = 0; c < CH2; ++c) sum += ctx_part[(size_t)c * CTX + idx];
        ctxTh[idx] = (_Float16)sum;
    } else {
        const int kidx = idx - CTX;
        if (kidx < BH * M_) {
            float sum = 0.f;
#pragma unroll
            for (int c = 0; c < CH2; ++c) sum += ksum_part[(size_t)c * BH * M_ + kidx];
            ksumh[kidx] = (_Float16)sum;
        }
    }
}

// ---------- Phase 3: out[n][d] = (q' ctx) / (q'.ksum) ----------
__global__ __launch_bounds__(256) void attn_out_mfma(
    const _Float16* __restrict__ qh, const _Float16* __restrict__ projh,
    const _Float16* __restrict__ ctxTh, const _Float16* __restrict__ ksumh,
    float* __restrict__ out)
{
    __shared__ __align__(16) _Float16 Sp[64 * 256];  // [n][m] swizzled (rows 512B, 32 blocks)

    const int tid  = threadIdx.x;
    const int lane = tid & 63;
    const int wv   = tid >> 6;
    const int lr = lane & 15, lg = lane >> 4;
    const int bh = blockIdx.y;
    const int bi = bh >> 4, h = bh & 15;
    const int n_base = blockIdx.x * (N_ / CH3);

    // proj A-frags: row m = 64wv+16I+lr, k=d
    half8 afP[4][2];
#pragma unroll
    for (int I = 0; I < 4; ++I)
#pragma unroll
        for (int ks = 0; ks < 2; ++ks)
            afP[I][ks] = *(const half8*)(projh + (size_t)(64 * wv + 16 * I + lr) * DH + 32 * ks + 8 * lg);

    for (int t = 0; t < (N_ / CH3) / 64; ++t) {
        const int n0 = n_base + t * 64;
        __syncthreads();                 // prev-iter Sp reads done
        // #1': S^T[m][n] = projh . Q^T   (B-frags from global qh)
        floatx4 sacc[4][4] = {};
#pragma unroll
        for (int ks = 0; ks < 2; ++ks) {
            half8 bq[4];
#pragma unroll
            for (int J = 0; J < 4; ++J)
                bq[J] = *(const half8*)(qh + ((size_t)bh * N_ + n0 + 16 * J + lr) * DH + 32 * ks + 8 * lg);
#pragma unroll
            for (int I = 0; I < 4; ++I)
#pragma unroll
                for (int J = 0; J < 4; ++J)
                    sacc[I][J] = __builtin_amdgcn_mfma_f32_16x16x32_f16(afP[I][ks], bq[J], sacc[I][J], 0, 0, 0);
        }
        // relu+eps -> Sp[n][m]
#pragma unroll
        for (int I = 0; I < 4; ++I)
#pragma unroll
            for (int J = 0; J < 4; ++J) {
                const int n = 16 * J + lr;
                const int m0 = 64 * wv + 16 * I + 4 * lg;
                half4v h4;
#pragma unroll
                for (int rg = 0; rg < 4; ++rg)
                    h4[rg] = (_Float16)(fmaxf(sacc[I][J][rg], 0.f) + EPS);
                const int db = m0 >> 3, sub = m0 & 7;
                *(half4v*)((char*)Sp + n * 512 + ((db ^ (n & 31)) * 16) + sub * 2) = h4;
            }
        __syncthreads();
        // #2: out rows [16wv,16wv+16): A=Sp, B=ctxTh (global, L2-hot), den via ksum column
        floatx4 oacc[4] = {};
        floatx4 dacc = {};
        const int nl = 16 * wv + lr;
#pragma unroll
        for (int ks = 0; ks < 8; ++ks) {
            half8 aq = *(const half8*)((const char*)Sp + nl * 512 + (((4 * ks + lg) ^ (nl & 31)) * 16));
#pragma unroll
            for (int j = 0; j < 4; ++j) {
                half8 bc = *(const half8*)(ctxTh + ((size_t)bh * DH + 16 * j + lr) * M_ + 32 * ks + 8 * lg);
                oacc[j] = __builtin_amdgcn_mfma_f32_16x16x32_f16(aq, bc, oacc[j], 0, 0, 0);
            }
            half8 bk = {};
            if (lr == 0)
                bk = *(const half8*)(ksumh + (size_t)bh * M_ + 32 * ks + 8 * lg);
            dacc = __builtin_amdgcn_mfma_f32_16x16x32_f16(aq, bk, dacc, 0, 0, 0);
        }
#pragma unroll
        for (int rg = 0; rg < 4; ++rg) {
            float den = dacc[rg];
            den = __shfl(den, lane & 48);       // broadcast from lr==0 of same quad
            const float dinv = 1.f / den;
            const int n = n0 + 16 * wv + 4 * lg + rg;
#pragma unroll
            for (int j = 0; j < 4; ++j)
                out[(((size_t)bi * N_ + n) * NH + h) * DH + 16 * j + lr] = oacc[j][rg] * dinv;
        }
    }
}

extern "C" void kernel_launch(void* const* d_in, const int* in_sizes, int n_in,
                              void* d_out, int out_size, void* d_ws, size_t ws_size,
                              hipStream_t stream) {
    const float* x    = (const float*)d_in[0];
    const float* w    = (const float*)d_in[1];
    const float* bias = (const float*)d_in[2];
    const float* proj = (const float*)d_in[3];
    float* out = (float*)d_out;
    char* ws = (char*)d_ws;

    const size_t QKV = (size_t)BH * N_ * DH;   // 16,777,216
    const size_t CTX = (size_t)BH * DH * M_;   // 1,048,576

    _Float16* wT       = (_Float16*)ws;                          ws += NC3 * HID * 2;
    _Float16* projh    = (_Float16*)ws;                          ws += M_ * DH * 2;
    _Float16* qh       = (_Float16*)ws;                          ws += QKV * 2;
    _Float16* kh       = (_Float16*)ws;                          ws += QKV * 2;
    _Float16* vTh      = (_Float16*)ws;                          ws += QKV * 2;
    _Float16* ctxTh    = (_Float16*)ws;                          ws += CTX * 2;
    _Float16* ksumh    = (_Float16*)ws;                          ws += BH * M_ * 2;
    float*    ctx_part = (float*)ws;                             ws += (size_t)CH2 * CTX * 4;
    float*    ksum_part= (float*)ws;                             ws += (size_t)CH2 * BH * M_ * 4;

    convert_wT<<<dim3(NC3 / 64, HID / 64), 256, 0, stream>>>(w, wT);
    convert_projh<<<dim3(M_ * DH / 256), 256, 0, stream>>>(proj, projh);

    gemm_qkv_mfma<<<dim3(NC3 / 128, (B_ * N_) / 128), 256, 0, stream>>>(x, wT, bias, qh, kh, vTh);

    kv_ctx_mfma<<<dim3(CH2, BH), 256, 0, stream>>>(kh, vTh, projh, ctx_part, ksum_part);

    reduce_ctx<<<dim3((CTX + BH * M_ + 255) / 256), 256, 0, stream>>>(ctx_part, ksum_part, ctxTh, ksumh);

    attn_out_mfma<<<dim3(CH3, BH), 256, 0, stream>>>(qh, projh, ctxTh, ksumh, out);
}

// Round 4
// 372.142 us; speedup vs baseline: 6.8791x; 1.1030x over previous
//
#include <hip/hip_runtime.h>

#define B_   4
#define N_   4096
#define NH   16
#define DH   64
#define HID  1024
#define NC3  3072
#define M_   256
#define BH   64
#define SCALE 0.125f
#define EPS   1e-3f
#define CH2  8
#define CH3  16

typedef _Float16 half8  __attribute__((ext_vector_type(8)));
typedef _Float16 half4v __attribute__((ext_vector_type(4)));
typedef float floatx4   __attribute__((ext_vector_type(4)));

#define GLD_LDS16(gptr, lds_base) \
  __builtin_amdgcn_global_load_lds((const __attribute__((address_space(1))) void*)(gptr), \
                                   (__attribute__((address_space(3))) void*)(lds_base), 16, 0, 0)

// ---------- xh = (f16) x ----------
__global__ __launch_bounds__(256) void convert_xh(
    const float* __restrict__ x, _Float16* __restrict__ xh)
{
    const size_t i = ((size_t)blockIdx.x * 256 + threadIdx.x) * 8;
    float4 a = *(const float4*)(x + i);
    float4 b = *(const float4*)(x + i + 4);
    half8 h;
    h[0] = (_Float16)a.x; h[1] = (_Float16)a.y; h[2] = (_Float16)a.z; h[3] = (_Float16)a.w;
    h[4] = (_Float16)b.x; h[5] = (_Float16)b.y; h[6] = (_Float16)b.z; h[7] = (_Float16)b.w;
    *(half8*)(xh + i) = h;
}

// ---------- wT[n][k] = (f16) w[k][n]  (q/k bands pre-scaled by d^-0.25) ----------
__global__ __launch_bounds__(256) void convert_wT(
    const float* __restrict__ w, _Float16* __restrict__ wT)
{
    __shared__ float t[64][65];
    const int tid = threadIdx.x;
    const int kb = blockIdx.y * 64, nb = blockIdx.x * 64;
    const int c = tid & 63, r0 = tid >> 6;
#pragma unroll
    for (int rr = 0; rr < 64; rr += 4)
        t[rr + r0][c] = w[(size_t)(kb + rr + r0) * NC3 + nb + c];
    __syncthreads();
    const float sc = (nb < 2048) ? SCALE : 1.0f;   // band is 64-wide: uniform per block
#pragma unroll
    for (int rr = 0; rr < 64; rr += 4)
        wT[(size_t)(nb + rr + r0) * HID + kb + c] = (_Float16)(t[c][rr + r0] * sc);
}

// ---------- projh = (f16) proj ----------
__global__ __launch_bounds__(256) void convert_projh(
    const float* __restrict__ proj, _Float16* __restrict__ projh)
{
    const int i = blockIdx.x * 256 + threadIdx.x;
    projh[i] = (_Float16)proj[i];
}

// ---------- Phase 1: qkv GEMM (f16 MFMA) -> qh,kh [bh][n][d] (scaled), vTh [bh][d][n] ----------
// A,B tiles both f16 128x32, rows 64B = 4 x 16B blocks, physical = logical ^ ((row>>1)&3)
__global__ __launch_bounds__(256) void gemm_qkv_mfma(
    const _Float16* __restrict__ xh, const _Float16* __restrict__ wT,
    const float* __restrict__ bias,
    _Float16* __restrict__ qh, _Float16* __restrict__ kh, _Float16* __restrict__ vTh)
{
    __shared__ __align__(16) _Float16 As[128 * 32];   // 8 KB
    __shared__ __align__(16) _Float16 Bs[128 * 32];   // 8 KB

    const int tid  = threadIdx.x;
    const int lane = tid & 63;
    const int wv   = tid >> 6;
    const int row0 = blockIdx.y * 128;
    const int col0 = blockIdx.x * 128;

    const int wm = (wv & 1) * 64;
    const int wn = (wv >> 1) * 64;
    const int lr = lane & 15;
    const int lg = lane >> 4;

    const int s_r = lane >> 2;        // staging: 16 rows / inst
    const int s_q = lane & 3;

    floatx4 acc[4][4] = {};

    for (int k0 = 0; k0 < HID; k0 += 32) {
#pragma unroll
        for (int s = 0; s < 2; ++s) {
            const int R = wv * 32 + s * 16;
            const int r = R + s_r;
            const int qd = s_q ^ ((r >> 1) & 3);
            GLD_LDS16(xh + (size_t)(row0 + r) * HID + k0 + 8 * qd, (char*)As + R * 64);
        }
#pragma unroll
        for (int s = 0; s < 2; ++s) {
            const int R = wv * 32 + s * 16;
            const int r = R + s_r;
            const int qd = s_q ^ ((r >> 1) & 3);
            GLD_LDS16(wT + (size_t)(col0 + r) * HID + k0 + 8 * qd, (char*)Bs + R * 64);
        }
        __syncthreads();

        half8 af[4], bf[4];
#pragma unroll
        for (int i = 0; i < 4; ++i) {
            const int m = wm + 16 * i + lr;
            const int p = lg ^ ((m >> 1) & 3);
            af[i] = *(const half8*)((const char*)As + m * 64 + p * 16);
        }
#pragma unroll
        for (int j = 0; j < 4; ++j) {
            const int n = wn + 16 * j + lr;
            const int p = lg ^ ((n >> 1) & 3);
            bf[j] = *(const half8*)((const char*)Bs + n * 64 + p * 16);
        }
#pragma unroll
        for (int i = 0; i < 4; ++i)
#pragma unroll
            for (int j = 0; j < 4; ++j)
                acc[i][j] = __builtin_amdgcn_mfma_f32_16x16x32_f16(af[i], bf[j], acc[i][j], 0, 0, 0);
        __syncthreads();
    }

#pragma unroll
    for (int j = 0; j < 4; ++j) {
        const int col = col0 + wn + 16 * j + lr;
        const int which = col >> 10;
        const int h = (col >> 6) & 15;
        const int d = col & 63;
        const float bb = bias[col] * ((which < 2) ? SCALE : 1.0f);
        if (which == 2) {
#pragma unroll
            for (int i = 0; i < 4; ++i) {
                const int m0 = row0 + wm + 16 * i + 4 * lg;
                const int bi = m0 >> 12, n0 = m0 & (N_ - 1);
                half4v hv;
#pragma unroll
                for (int rg = 0; rg < 4; ++rg) hv[rg] = (_Float16)(acc[i][j][rg] + bb);
                *(half4v*)(vTh + ((size_t)(bi * NH + h) * DH + d) * N_ + n0) = hv;
            }
        } else {
            _Float16* dst = (which == 0) ? qh : kh;
#pragma unroll
            for (int i = 0; i < 4; ++i)
#pragma unroll
                for (int rg = 0; rg < 4; ++rg) {
                    const int m = row0 + wm + 16 * i + 4 * lg + rg;
                    const int bi = m >> 12, n = m & (N_ - 1);
                    dst[((size_t)(bi * NH + h) * N_ + n) * DH + d] =
                        (_Float16)(acc[i][j][rg] + bb);
                }
        }
    }
}

// ---------- Phase 2: per (chunk,bh): ctxT_part[d][m] = sum_n vT[d][n] * k'[n][m] ----------
__global__ __launch_bounds__(256) void kv_ctx_mfma(
    const _Float16* __restrict__ kh, const _Float16* __restrict__ vTh,
    const _Float16* __restrict__ projh,
    float* __restrict__ ctx_part, float* __restrict__ ksum_part)
{
    __shared__ __align__(16) _Float16 Kt[64 * 64];   // [n][d] swizzled
    __shared__ __align__(16) _Float16 Vt[64 * 64];   // [d][n] swizzled
    __shared__ __align__(16) _Float16 Sp[256 * 64];  // [m][n] swizzled, wave-private slices

    const int tid  = threadIdx.x;
    const int lane = tid & 63;
    const int wv   = tid >> 6;
    const int lr = lane & 15, lg = lane >> 4;
    const int bh = blockIdx.y, chunk = blockIdx.x;
    const int n_base = chunk * (N_ / CH2);

    half8 bfP[4][2];
#pragma unroll
    for (int j = 0; j < 4; ++j)
#pragma unroll
        for (int ks = 0; ks < 2; ++ks)
            bfP[j][ks] = *(const half8*)(projh + (size_t)(64 * wv + 16 * j + lr) * DH + 32 * ks + 8 * lg);

    floatx4 cacc[4][4] = {};
    float ks_acc[4] = {0.f, 0.f, 0.f, 0.f};

    for (int t = 0; t < (N_ / CH2) / 64; ++t) {
        const int n0 = n_base + t * 64;
        __syncthreads();
#pragma unroll
        for (int s = 0; s < 2; ++s) {
            const int R = wv * 16 + s * 8;
            const int r = R + (lane >> 3);
            const int db = (lane & 7) ^ (r & 7);
            GLD_LDS16(kh + ((size_t)(bh * N_ + n0 + r)) * DH + db * 8, (char*)Kt + R * 128);
        }
#pragma unroll
        for (int s = 0; s < 2; ++s) {
            const int R = wv * 16 + s * 8;
            const int r = R + (lane >> 3);
            const int db = (lane & 7) ^ (r & 7);
            GLD_LDS16(vTh + ((size_t)(bh * DH + r)) * N_ + n0 + db * 8, (char*)Vt + R * 128);
        }
        __syncthreads();

        floatx4 s[4][4] = {};
#pragma unroll
        for (int ks = 0; ks < 2; ++ks) {
            half8 aK[4];
#pragma unroll
            for (int i = 0; i < 4; ++i) {
                const int r = 16 * i + lr;
                aK[i] = *(const half8*)((const char*)Kt + r * 128 + (((4 * ks + lg) ^ (r & 7)) * 16));
            }
#pragma unroll
            for (int i = 0; i < 4; ++i)
#pragma unroll
                for (int j = 0; j < 4; ++j)
                    s[i][j] = __builtin_amdgcn_mfma_f32_16x16x32_f16(aK[i], bfP[j][ks], s[i][j], 0, 0, 0);
        }
#pragma unroll
        for (int i = 0; i < 4; ++i)
#pragma unroll
            for (int j = 0; j < 4; ++j) {
                const int m = 64 * wv + 16 * j + lr;
                const int nn0 = 16 * i + 4 * lg;
                half4v h4;
#pragma unroll
                for (int rg = 0; rg < 4; ++rg) {
                    const float kv = fmaxf(s[i][j][rg], 0.f) + EPS;
                    ks_acc[j] += kv;
                    h4[rg] = (_Float16)kv;
                }
                const int db = nn0 >> 3, sub = nn0 & 7;
                *(half4v*)((char*)Sp + m * 128 + ((db ^ (m & 7)) * 16) + sub * 2) = h4;
            }
#pragma unroll
        for (int ks = 0; ks < 2; ++ks) {
            half8 aV[4], bS[4];
#pragma unroll
            for (int i = 0; i < 4; ++i) {
                const int r = 16 * i + lr;
                aV[i] = *(const half8*)((const char*)Vt + r * 128 + (((4 * ks + lg) ^ (r & 7)) * 16));
            }
#pragma unroll
            for (int j = 0; j < 4; ++j) {
                const int m = 64 * wv + 16 * j + lr;
                bS[j] = *(const half8*)((const char*)Sp + m * 128 + (((4 * ks + lg) ^ (m & 7)) * 16));
            }
#pragma unroll
            for (int i = 0; i < 4; ++i)
#pragma unroll
                for (int j = 0; j < 4; ++j)
                    cacc[i][j] = __builtin_amdgcn_mfma_f32_16x16x32_f16(aV[i], bS[j], cacc[i][j], 0, 0, 0);
        }
    }

#pragma unroll
    for (int i = 0; i < 4; ++i)
#pragma unroll
        for (int j = 0; j < 4; ++j)
#pragma unroll
            for (int rg = 0; rg < 4; ++rg) {
                const int d = 16 * i + 4 * lg + rg;
                const int m = 64 * wv + 16 * j + lr;
                ctx_part[(((size_t)chunk * BH + bh) * DH + d) * M_ + m] = cacc[i][j][rg];
            }
#pragma unroll
    for (int j = 0; j < 4; ++j) {
        float v = ks_acc[j];
        v += __shfl_xor(v, 16);
        v += __shfl_xor(v, 32);
        if (lg == 0)
            ksum_part[((size_t)chunk * BH + bh) * M_ + 64 * wv + 16 * j + lr] = v;
    }
}

// ---------- reduce partials -> ctxTh f16 [bh][d][m], ksumh f16 [bh][m] ----------
__global__ __launch_bounds__(256) void reduce_ctx(
    const float* __restrict__ ctx_part, const float* __restrict__ ksum_part,
    _Float16* __restrict__ ctxTh, _Float16* __restrict__ ksumh)
{
    const int idx = blockIdx.x * 256 + threadIdx.x;
    const int CTX = BH * DH * M_;
    if (idx < CTX) {
        float sum = 0.f;
#pragma unroll
        for (int c = 0; c < CH2; ++c) sum += ctx_part[(size_t)c * CTX + idx];
        ctxTh[idx] = (_Float16)sum;
    } else {
        const int kidx = idx - CTX;
        if (kidx < BH * M_) {
            float sum = 0.f;
#pragma unroll
            for (int c = 0; c < CH2; ++c) sum += ksum_part[(size_t)c * BH * M_ + kidx];
            ksumh[kidx] = (_Float16)sum;
        }
    }
}

// ---------- Phase 3: out[n][d] = (q' ctx) / (q'.ksum) ----------
__global__ __launch_bounds__(256) void attn_out_mfma(
    const _Float16* __restrict__ qh, const _Float16* __restrict__ projh,
    const _Float16* __restrict__ ctxTh, const _Float16* __restrict__ ksumh,
    float* __restrict__ out)
{
    __shared__ __align__(16) _Float16 Sp[64 * 256];

    const int tid  = threadIdx.x;
    const int lane = tid & 63;
    const int wv   = tid >> 6;
    const int lr = lane & 15, lg = lane >> 4;
    const int bh = blockIdx.y;
    const int bi = bh >> 4, h = bh & 15;
    const int n_base = blockIdx.x * (N_ / CH3);

    half8 afP[4][2];
#pragma unroll
    for (int I = 0; I < 4; ++I)
#pragma unroll
        for (int ks = 0; ks < 2; ++ks)
            afP[I][ks] = *(const half8*)(projh + (size_t)(64 * wv + 16 * I + lr) * DH + 32 * ks + 8 * lg);

    for (int t = 0; t < (N_ / CH3) / 64; ++t) {
        const int n0 = n_base + t * 64;
        __syncthreads();
        floatx4 sacc[4][4] = {};
#pragma unroll
        for (int ks = 0; ks < 2; ++ks) {
            half8 bq[4];
#pragma unroll
            for (int J = 0; J < 4; ++J)
                bq[J] = *(const half8*)(qh + ((size_t)bh * N_ + n0 + 16 * J + lr) * DH + 32 * ks + 8 * lg);
#pragma unroll
            for (int I = 0; I < 4; ++I)
#pragma unroll
                for (int J = 0; J < 4; ++J)
                    sacc[I][J] = __builtin_amdgcn_mfma_f32_16x16x32_f16(afP[I][ks], bq[J], sacc[I][J], 0, 0, 0);
        }
#pragma unroll
        for (int I = 0; I < 4; ++I)
#pragma unroll
            for (int J = 0; J < 4; ++J) {
                const int n = 16 * J + lr;
                const int m0 = 64 * wv + 16 * I + 4 * lg;
                half4v h4;
#pragma unroll
                for (int rg = 0; rg < 4; ++rg)
                    h4[rg] = (_Float16)(fmaxf(sacc[I][J][rg], 0.f) + EPS);
                const int db = m0 >> 3, sub = m0 & 7;
                *(half4v*)((char*)Sp + n * 512 + ((db ^ (n & 31)) * 16) + sub * 2) = h4;
            }
        __syncthreads();
        floatx4 oacc[4] = {};
        floatx4 dacc = {};
        const int nl = 16 * wv + lr;
#pragma unroll
        for (int ks = 0; ks < 8; ++ks) {
            half8 aq = *(const half8*)((const char*)Sp + nl * 512 + (((4 * ks + lg) ^ (nl & 31)) * 16));
#pragma unroll
            for (int j = 0; j < 4; ++j) {
                half8 bc = *(const half8*)(ctxTh + ((size_t)bh * DH + 16 * j + lr) * M_ + 32 * ks + 8 * lg);
                oacc[j] = __builtin_amdgcn_mfma_f32_16x16x32_f16(aq, bc, oacc[j], 0, 0, 0);
            }
            half8 bk = {};
            if (lr == 0)
                bk = *(const half8*)(ksumh + (size_t)bh * M_ + 32 * ks + 8 * lg);
            dacc = __builtin_amdgcn_mfma_f32_16x16x32_f16(aq, bk, dacc, 0, 0, 0);
        }
#pragma unroll
        for (int rg = 0; rg < 4; ++rg) {
            float den = dacc[rg];
            den = __shfl(den, lane & 48);
            const float dinv = 1.f / den;
            const int n = n0 + 16 * wv + 4 * lg + rg;
#pragma unroll
            for (int j = 0; j < 4; ++j)
                out[(((size_t)bi * N_ + n) * NH + h) * DH + 16 * j + lr] = oacc[j][rg] * dinv;
        }
    }
}

extern "C" void kernel_launch(void* const* d_in, const int* in_sizes, int n_in,
                              void* d_out, int out_size, void* d_ws, size_t ws_size,
                              hipStream_t stream) {
    const float* x    = (const float*)d_in[0];
    const float* w    = (const float*)d_in[1];
    const float* bias = (const float*)d_in[2];
    const float* proj = (const float*)d_in[3];
    float* out = (float*)d_out;
    char* ws = (char*)d_ws;

    const size_t XN  = (size_t)B_ * N_ * HID;  // 16,777,216
    const size_t QKV = (size_t)BH * N_ * DH;   // 16,777,216
    const size_t CTX = (size_t)BH * DH * M_;   // 1,048,576

    _Float16* xh       = (_Float16*)ws;                          ws += XN * 2;
    _Float16* wT       = (_Float16*)ws;                          ws += NC3 * HID * 2;
    _Float16* projh    = (_Float16*)ws;                          ws += M_ * DH * 2;
    _Float16* qh       = (_Float16*)ws;                          ws += QKV * 2;
    _Float16* kh       = (_Float16*)ws;                          ws += QKV * 2;
    _Float16* vTh      = (_Float16*)ws;                          ws += QKV * 2;
    _Float16* ctxTh    = (_Float16*)ws;                          ws += CTX * 2;
    _Float16* ksumh    = (_Float16*)ws;                          ws += BH * M_ * 2;
    float*    ctx_part = (float*)ws;                             ws += (size_t)CH2 * CTX * 4;
    float*    ksum_part= (float*)ws;                             ws += (size_t)CH2 * BH * M_ * 4;

    convert_xh<<<dim3(XN / (256 * 8)), 256, 0, stream>>>(x, xh);
    convert_wT<<<dim3(NC3 / 64, HID / 64), 256, 0, stream>>>(w, wT);
    convert_projh<<<dim3(M_ * DH / 256), 256, 0, stream>>>(proj, projh);

    gemm_qkv_mfma<<<dim3(NC3 / 128, (B_ * N_) / 128), 256, 0, stream>>>(xh, wT, bias, qh, kh, vTh);

    kv_ctx_mfma<<<dim3(CH2, BH), 256, 0, stream>>>(kh, vTh, projh, ctx_part, ksum_part);

    reduce_ctx<<<dim3((CTX + BH * M_ + 255) / 256), 256, 0, stream>>>(ctx_part, ksum_part, ctxTh, ksumh);

    attn_out_mfma<<<dim3(CH3, BH), 256, 0, stream>>>(qh, projh, ctxTh, ksumh, out);
}